// Round 5
// baseline (339.614 us; speedup 1.0000x reference)
//
#include <hip/hip_runtime.h>
#include <hip/hip_bf16.h>

#define T_SEQ 4096
#define DIM   256
#define NBATCH 4

typedef short s8v __attribute__((ext_vector_type(8)));   // 8 bf16 (A/B frag)
typedef float f4v __attribute__((ext_vector_type(4)));   // 4 fp32 (C/D frag)
typedef unsigned short u16;

#define MFMA16(a,b,c) __builtin_amdgcn_mfma_f32_16x16x32_bf16(a,b,c,0,0,0)
#define FENCE_LGKM() asm volatile("s_waitcnt lgkmcnt(0)" ::: "memory")

// dynamic task counters, one per batch; zeroed by wtrans_kernel each launch
__device__ int g_cnt[4];

static __device__ __forceinline__ u16 f2bf(float f) {
  union { float f; unsigned int u; } c; c.f = f;
  unsigned int u = c.u;
  unsigned int r = (u + 0x7fffu + ((u >> 16) & 1u)) >> 16;   // RNE
  return (u16)r;
}

// pack 8 consecutive fp32 -> 8 bf16 (A-frag source)
static __device__ __forceinline__ s8v pack8(const float* p) {
  float4 a = *(const float4*)p;
  float4 b = *(const float4*)(p + 4);
  s8v r;
  r[0] = (short)f2bf(a.x); r[1] = (short)f2bf(a.y);
  r[2] = (short)f2bf(a.z); r[3] = (short)f2bf(a.w);
  r[4] = (short)f2bf(b.x); r[5] = (short)f2bf(b.y);
  r[6] = (short)f2bf(b.z); r[7] = (short)f2bf(b.w);
  return r;
}

// ---------- diagnostic fallback (fp32 out) ----------
__global__ void diag_fill_kernel(float* __restrict__ out, float val, int n) {
  int i = blockIdx.x * blockDim.x + threadIdx.x;
  if (i < n) out[i] = val;
}

// ---------- kernel 1: Wt[n][k] = bf16(W[k][n]) for the 3 weight matrices ----------
__global__ void wtrans_kernel(const float* __restrict__ Wq, const float* __restrict__ Wk,
                              const float* __restrict__ Wv, u16* __restrict__ Wt) {
  if (blockIdx.x == 0 && blockIdx.y == 0 && blockIdx.z == 0 &&
      threadIdx.y == 0 && threadIdx.x < 4)
    g_cnt[threadIdx.x] = 0;                    // reset attn task queues (stream-ordered)
  __shared__ float tile[32][33];
  int m = blockIdx.z;
  const float* W = (m == 0) ? Wq : ((m == 1) ? Wk : Wv);
  int bx = blockIdx.x * 32, by = blockIdx.y * 32;
  int x = threadIdx.x, y = threadIdx.y;          // block (32,8)
  #pragma unroll
  for (int i = 0; i < 32; i += 8) tile[y + i][x] = W[(by + y + i) * DIM + bx + x];
  __syncthreads();
  u16* o = Wt + m * DIM * DIM;
  #pragma unroll
  for (int i = 0; i < 32; i += 8) o[(bx + y + i) * DIM + by + x] = f2bf(tile[x][y + i]);
}

// ---------- kernel 2: K / V^T projections -> FRAGMENT-MAJOR tile format ------
// (unchanged)
__global__ __launch_bounds__(256) void proj_kernel(
    const float* __restrict__ x, const u16* __restrict__ Wt,
    const float* __restrict__ bk, const float* __restrict__ bv,
    u16* __restrict__ kf, u16* __restrict__ vf) {
  alignas(16) __shared__ u16 Kl[64 * 264];       // K rows, pad 256->264
  alignas(16) __shared__ u16 Vl[256 * 72];       // V^T [c][t_local], pad 64->72

  int bid = blockIdx.x;
  int which = blockIdx.y;                        // 0 = K, 1 = V
  int tid  = threadIdx.x;
  int wave = tid >> 6, lane = tid & 63, quad = lane >> 4, l16 = lane & 15;
  int row0 = bid * 64 + wave * 16;

  s8v a[8];
  const float* xp = x + (size_t)(row0 + l16) * DIM + quad * 8;
  #pragma unroll
  for (int ks = 0; ks < 8; ks++) a[ks] = pack8(xp + ks * 32);

  if (which == 0) {
    const u16* W = Wt + DIM * DIM;               // Wk^T
    f4v acc[16];
    #pragma unroll
    for (int nt = 0; nt < 16; nt++) acc[nt] = (f4v){0.f, 0.f, 0.f, 0.f};
    #pragma unroll
    for (int ks = 0; ks < 8; ks++) {
      #pragma unroll
      for (int nt = 0; nt < 16; nt++) {
        s8v bfr = *(const s8v*)(W + (nt * 16 + l16) * DIM + ks * 32 + quad * 8);
        acc[nt] = MFMA16(a[ks], bfr, acc[nt]);
      }
    }
    #pragma unroll
    for (int nt = 0; nt < 16; nt++) {
      float bb = bk[nt * 16 + l16];
      #pragma unroll
      for (int r = 0; r < 4; r++)
        Kl[(wave * 16 + quad * 4 + r) * 264 + nt * 16 + l16] = f2bf(acc[nt][r] + bb);
    }
    __syncthreads();
    #pragma unroll
    for (int i = 0; i < 8; i++) {                // 2048 chunks, 8/thread
      int o = tid + i * 256;
      int tile = o >> 10, rem = o & 1023;
      int f = rem >> 6, ln = rem & 63;
      int sl = tile * 32 + (f >> 3) * 16 + (ln & 15);
      int c  = (f & 7) * 32 + (ln >> 4) * 8;
      s8v v = *(const s8v*)&Kl[sl * 264 + c];
      *(s8v*)&kf[(((size_t)(bid * 2 + tile) * 16 + f) * 64 + ln) * 8] = v;
    }
  } else {
    const u16* W = Wt + 2 * DIM * DIM;           // Wv^T
    f4v acc[16];
    #pragma unroll
    for (int nt = 0; nt < 16; nt++) acc[nt] = (f4v){0.f, 0.f, 0.f, 0.f};
    #pragma unroll
    for (int ks = 0; ks < 8; ks++) {
      #pragma unroll
      for (int nt = 0; nt < 16; nt++) {
        s8v bfr = *(const s8v*)(W + (nt * 16 + l16) * DIM + ks * 32 + quad * 8);
        acc[nt] = MFMA16(a[ks], bfr, acc[nt]);
      }
    }
    #pragma unroll
    for (int nt = 0; nt < 16; nt++) {
      float bb = bv[nt * 16 + l16];
      union { u16 h[4]; uint2 v2; } pk;
      #pragma unroll
      for (int r = 0; r < 4; r++) pk.h[r] = f2bf(acc[nt][r] + bb);
      *(uint2*)&Vl[(nt * 16 + l16) * 72 + wave * 16 + quad * 4] = pk.v2;
    }
    __syncthreads();
    #pragma unroll
    for (int i = 0; i < 8; i++) {                // 2048 chunks, 8/thread
      int o = tid + i * 256;
      int tile = o >> 10, rem = o & 1023;
      int nt = rem >> 6, ln = rem & 63;
      int c  = nt * 16 + (ln & 15);
      int sl = tile * 32 + (ln >> 4) * 8;
      s8v v = *(const s8v*)&Vl[c * 72 + sl];
      *(s8v*)&vf[(((size_t)(bid * 2 + tile) * 16 + nt) * 64 + ln) * 8] = v;
    }
  }
}

// ---------- kernel 2.5: zero out + lsum (runs after proj, before attn) -------
__global__ void zero_kernel(float* __restrict__ out, float* __restrict__ lsum,
                            int nOut, int nL) {
  int i = blockIdx.x * blockDim.x + threadIdx.x;
  int stride = gridDim.x * blockDim.x;
  for (int k = i; k < nOut; k += stride) out[k] = 0.f;
  for (int k = i; k < nL; k += stride) lsum[k] = 0.f;
}

// ---------- kernel 3 v4: flash attention, LDS-shared K/V, split-KV atomics ---
// THEORY (r3 counters): occupancy 15->19.7% gave ZERO speedup; HBM 5.6%;
// => L2/L3-BW-bound: 66K wave-iters x 32KB K+V = 2.1 GB from L2/L3 per launch.
// FIX: 4 slab-waves per block SHARE each K/V tile via LDS (L2 traffic /4).
// Balance: subtask = (64-row tile, kv-quarter) -> 1024 near-uniform subtasks
// (<=64 iters), dynamic descending. No-max softmax is linear in partials =>
// combine via fp32 atomicAdd into out + lsum, normalize in a final pass.
// Pipeline per iter: issue next-tile global loads EARLY (regs), consume cur
// LDS buffer (S, exp, Ps, PV), ds_write staged regs LATE, one barrier (T14).
__global__ __launch_bounds__(256, 2) void attn_kernel(
    const float* __restrict__ x, const u16* __restrict__ wtq, const float* __restrict__ bq,
    const u16* __restrict__ kf, const u16* __restrict__ vf,
    float* __restrict__ lsum, float* __restrict__ out) {
  alignas(16) __shared__ u16 KV[2][16384];        // 64 KB: [buf][ K 8192 u16 | V 8192 u16 ]
  alignas(16) __shared__ u16 Ps[4 * 640];         // per-wave P staging, stride 40
  __shared__ int taskS;
  u16* Qs = &KV[0][0];                            // Q staging aliases KV (pre-loop only;
                                                  // stride-264 rows spill into KV[1] region,
                                                  // still inside the 32768-u16 block, dead
                                                  // before buf-1 staging begins)

  int bid = blockIdx.x;
  int b = bid & 3;
  int tid = threadIdx.x;
  int w = tid >> 6, lane = tid & 63, quad = lane >> 4, l16 = lane & 15;

  const u16* kfb = kf + (size_t)b * 128 * 8192;
  const u16* vfb = vf + (size_t)b * 128 * 8192;

  for (;;) {
    if (tid == 0) taskS = atomicAdd(&g_cnt[b], 1);
    __syncthreads();                              // also orders prev-task LDS reads
    int t = taskS;
    if (t >= 256) break;
    int q64 = 63 - (t >> 2);                      // 64-row tile, biggest first
    int qi  = t & 3;                              // kv quarter
    int row0 = q64 * 64;
    int n = 2 * q64 + 2;                          // causal kv-tile count for this tile
    int lo = (n * qi) >> 2, hi = (n * (qi + 1)) >> 2;
    if (lo >= hi) continue;                       // empty quarter (q64=0), block-uniform

    // ---- Q projection: wave w computes cols [w*64, w*64+64) for ALL 64 rows,
    //      W-frags loaded once per (ks,j) and reused across the 4 slabs. ----
    {
      f4v qacc[4][4];
      #pragma unroll
      for (int g = 0; g < 4; g++)
        #pragma unroll
        for (int j = 0; j < 4; j++) qacc[g][j] = (f4v){0.f, 0.f, 0.f, 0.f};
      #pragma unroll
      for (int ks = 0; ks < 8; ks++) {
        s8v wf[4];
        #pragma unroll
        for (int j = 0; j < 4; j++)
          wf[j] = *(const s8v*)(wtq + ((w * 4 + j) * 16 + l16) * DIM + ks * 32 + quad * 8);
        #pragma unroll
        for (int g = 0; g < 4; g++) {
          s8v xa = pack8(x + (size_t)(b * T_SEQ + row0 + g * 16 + l16) * DIM + ks * 32 + quad * 8);
          #pragma unroll
          for (int j = 0; j < 4; j++) qacc[g][j] = MFMA16(xa, wf[j], qacc[g][j]);
        }
      }
      #pragma unroll
      for (int j = 0; j < 4; j++) {
        int nt = w * 4 + j;
        float bb = bq[nt * 16 + l16];
        #pragma unroll
        for (int g = 0; g < 4; g++)
          #pragma unroll
          for (int r = 0; r < 4; r++)
            Qs[(g * 16 + quad * 4 + r) * 264 + nt * 16 + l16] =
                f2bf((qacc[g][j][r] + bb) * 0.0625f);   // pre-scale 1/sqrt(256)
      }
    }
    __syncthreads();                              // Q staged (in KV region)
    s8v qa[8];
    #pragma unroll
    for (int ks = 0; ks < 8; ks++)
      qa[ks] = *(const s8v*)&Qs[(w * 16 + l16) * 264 + ks * 32 + quad * 8];
    __syncthreads();                              // all qa read before KV reuse

    int rowBase = row0 + w * 16;                  // wave = slab

    f4v o[16];
    #pragma unroll
    for (int nt = 0; nt < 16; nt++) o[nt] = (f4v){0.f, 0.f, 0.f, 0.f};
    float lrow[4] = {0.f, 0.f, 0.f, 0.f};

    // ---- prologue: stage tile lo into buf 0 (each wave stages 4KB K + 4KB V)
    uint4 st[8];
    {
      const u16* kp = kfb + ((size_t)lo << 13) + (w << 11) + (lane << 3);
      const u16* vp = vfb + ((size_t)lo << 13) + (w << 11) + (lane << 3);
      #pragma unroll
      for (int i = 0; i < 4; i++) {
        st[i]     = *(const uint4*)(kp + (i << 9));
        st[4 + i] = *(const uint4*)(vp + (i << 9));
      }
      u16* kd = &KV[0][(w << 11) + (lane << 3)];
      #pragma unroll
      for (int i = 0; i < 4; i++) {
        *(uint4*)(kd + (i << 9))        = st[i];
        *(uint4*)(kd + 8192 + (i << 9)) = st[4 + i];
      }
    }
    __syncthreads();

    #pragma unroll 1
    for (int kv = lo; kv < hi; kv++) {
      int cur = (kv - lo) & 1;
      bool more = (kv + 1 < hi);

      // issue next tile's global loads EARLY (latency hidden under compute)
      if (more) {
        const u16* kp = kfb + ((size_t)(kv + 1) << 13) + (w << 11) + (lane << 3);
        const u16* vp = vfb + ((size_t)(kv + 1) << 13) + (w << 11) + (lane << 3);
        #pragma unroll
        for (int i = 0; i < 4; i++) {
          st[i]     = *(const uint4*)(kp + (i << 9));
          st[4 + i] = *(const uint4*)(vp + (i << 9));
        }
      }

      // ---- consume buf[cur]: S = Q K^T ----
      f4v c0 = (f4v){0.f, 0.f, 0.f, 0.f}, c1 = (f4v){0.f, 0.f, 0.f, 0.f};
      {
        s8v kfr[8];
        #pragma unroll
        for (int f = 0; f < 8; f++) kfr[f] = *(const s8v*)&KV[cur][(f << 9) + (lane << 3)];
        #pragma unroll
        for (int ks = 0; ks < 8; ks++) c0 = MFMA16(qa[ks], kfr[ks], c0);
        #pragma unroll
        for (int f = 0; f < 8; f++) kfr[f] = *(const s8v*)&KV[cur][((8 + f) << 9) + (lane << 3)];
        #pragma unroll
        for (int ks = 0; ks < 8; ks++) c1 = MFMA16(qa[ks], kfr[ks], c1);
      }

      // p = exp(s); causal mask -> exact 0
      int s0 = kv * 32 + l16;
      #pragma unroll
      for (int r = 0; r < 4; r++) {
        int tq = rowBase + quad * 4 + r;
        float v0 = (s0 > tq)      ? -1e30f : c0[r];
        float v1 = (s0 + 16 > tq) ? -1e30f : c1[r];
        float p0 = __expf(v0);
        float p1 = __expf(v1);
        Ps[w * 640 + (quad * 4 + r) * 40 + l16]      = f2bf(p0);
        Ps[w * 640 + (quad * 4 + r) * 40 + 16 + l16] = f2bf(p1);
        lrow[r] += p0 + p1;
      }
      FENCE_LGKM();                               // Ps write->read (same wave)
      s8v pa = *(const s8v*)&Ps[w * 640 + l16 * 40 + quad * 8];

      // ---- PV from LDS V frags ----
      {
        s8v vfr[8];
        #pragma unroll
        for (int f = 0; f < 8; f++) vfr[f] = *(const s8v*)&KV[cur][8192 + (f << 9) + (lane << 3)];
        #pragma unroll
        for (int nt = 0; nt < 8; nt++) o[nt] = MFMA16(pa, vfr[nt], o[nt]);
        #pragma unroll
        for (int f = 0; f < 8; f++) vfr[f] = *(const s8v*)&KV[cur][8192 + ((8 + f) << 9) + (lane << 3)];
        #pragma unroll
        for (int nt = 0; nt < 8; nt++) o[8 + nt] = MFMA16(pa, vfr[nt], o[8 + nt]);
      }

      // write staged regs into the other buffer LATE (compiler waits vmcnt)
      if (more) {
        u16* kd = &KV[cur ^ 1][(w << 11) + (lane << 3)];
        #pragma unroll
        for (int i = 0; i < 4; i++) {
          *(uint4*)(kd + (i << 9))        = st[i];
          *(uint4*)(kd + 8192 + (i << 9)) = st[4 + i];
        }
      }
      __syncthreads();
    }

    // ---- epilogue: additive combine via device atomics ----
    #pragma unroll
    for (int r = 0; r < 4; r++) {
      #pragma unroll
      for (int d = 1; d < 16; d <<= 1) lrow[r] += __shfl_xor(lrow[r], d);
    }
    if (l16 == 0) {
      #pragma unroll
      for (int r = 0; r < 4; r++)
        atomicAdd(&lsum[b * T_SEQ + rowBase + quad * 4 + r], lrow[r]);
    }
    #pragma unroll
    for (int nt = 0; nt < 16; nt++) {
      #pragma unroll
      for (int r = 0; r < 4; r++)
        atomicAdd(&out[(size_t)(b * T_SEQ + rowBase + quad * 4 + r) * DIM + nt * 16 + l16],
                  o[nt][r]);
    }
  }
}

// ---------- kernel 4: normalize out by row sums ----------
__global__ void norm_kernel(float* __restrict__ out, const float* __restrict__ lsum, int n) {
  int i = blockIdx.x * blockDim.x + threadIdx.x;
  if (i < n) out[i] *= (1.0f / lsum[i >> 8]);
}

extern "C" void kernel_launch(void* const* d_in, const int* in_sizes, int n_in,
                              void* d_out, int out_size, void* d_ws, size_t ws_size,
                              hipStream_t stream) {
  const float* x  = (const float*)d_in[0];
  const float* Wq = (const float*)d_in[1];
  const float* bq = (const float*)d_in[2];
  const float* Wk = (const float*)d_in[3];
  const float* bk = (const float*)d_in[4];
  const float* Wv = (const float*)d_in[5];
  const float* bv = (const float*)d_in[6];

  const size_t NTD = (size_t)NBATCH * T_SEQ * DIM;             // 4,194,304 elems
  const size_t WT_ELEMS = (size_t)3 * DIM * DIM;               //   196,608 elems
  const size_t REQ_BYTES = (WT_ELEMS + 2 * NTD) * sizeof(u16); // 17,170,432 B

  if (ws_size < REQ_BYTES) {
    float val = (float)(ws_size >> 20);   // diagnostic: absmax encodes ws MiB
    diag_fill_kernel<<<(out_size + 255) / 256, 256, 0, stream>>>((float*)d_out, val, out_size);
    return;
  }

  u16* ws = (u16*)d_ws;
  u16* WT = ws;                    // [0]=Wq^T [1]=Wk^T [2]=Wv^T, 384 KiB
  u16* Kf = ws + WT_ELEMS;         // 8 MiB, frag-major K tiles
  u16* Vf = Kf + NTD;              // 8 MiB, frag-major V^T tiles
  // lsum reuses the Wv^T slot (131072 B >= 65536 B needed); proj_kernel is the
  // last reader of Wv^T and runs before zero_kernel in stream order.
  // (r4 BUGFIX: was ws + 3*DIM*DIM, which aliased Kf and corrupted K tiles.)
  float* lsum = (float*)(ws + 2 * (size_t)DIM * DIM);

  const int nOut = NBATCH * T_SEQ * DIM;         // 4,194,304 floats
  const int nL   = NBATCH * T_SEQ;               //    16,384 floats

  wtrans_kernel<<<dim3(8, 8, 3), dim3(32, 8, 1), 0, stream>>>(Wq, Wk, Wv, WT);
  proj_kernel<<<dim3(256, 2, 1), dim3(256, 1, 1), 0, stream>>>(x, WT, bk, bv, Kf, Vf);
  zero_kernel<<<2048, 256, 0, stream>>>((float*)d_out, lsum, nOut, nL);
  attn_kernel<<<dim3(512, 1, 1), dim3(256, 1, 1), 0, stream>>>(x, WT, bq, Kf, Vf, lsum, (float*)d_out);
  norm_kernel<<<(nOut + 255) / 256, 256, 0, stream>>>((float*)d_out, lsum, nOut);
}